// Round 1
// baseline (94.566 us; speedup 1.0000x reference)
//
#include <hip/hip_runtime.h>
#include <hip/hip_bf16.h>

// SplineLoss: reference evaluates a not-a-knot cubic spline at INTEGER sample
// times t=0,10,...,8190 with knots at integers 0..8191 -> local parameter is
// exactly 0 for every sample, so the spline solve vanishes and the result is
// exactly:  mean_{b<1024, j<820} (true[b,10j] - pred[b,10j])^2
//
// Stride 40B < 64B line -> every line of both 32MB inputs is needed; minimum
// traffic 64MB, roofline ~10.2us at 6.3TB/s. Within float4 group g (t=4g),
// samples land at .x when g%5==0 and .z when g%5==2.
//
// R3 lesson 1: per-block agent-scope acq_rel fences are catastrophic
// (~+90us for 2048 blocks) -> two-dispatch reduction, no device fences.
// R3 lesson 2: the R1/R2 loop compiled to VGPR=12 -> only ~2 loads in
// flight -> latency-bound at ~450GB/s effective (213GB/s HBM-side).
// Fix: load all 8 float4s into named registers BEFORE any use -> 8
// independent global_load_dwordx4 in flight (8KB/wave MLP).
//
// R4: container failed twice (infra, not kernel) -> zero counters this
// round. Deliberate re-baseline of the verified 91.3us kernel, unchanged.
// Open hypotheses for the 91.3us vs ~10.2us roofline gap, to be decided
// by this round's counters:
//   H1 clock/DVFS floor on a short kernel   -> low hbm_gbps, all else nominal
//   H2 timing floor outside the kernel      -> dispatch dur_us << wall time
//   H3 inputs L2/L3-resident after poison   -> FETCH_SIZE << 64MB
//   H4 residual latency-boundness           -> FETCH ~64MB, low hbm_pct_peak

#define B_ROWS   1024
#define N_COLS   8192
#define N_SAMP   820
#define BLOCK    256
#define SPLIT    2                         // blocks per row
#define GRID     (B_ROWS * SPLIT)          // 2048 partials
#define GROUPS_PER_ROW   (N_COLS / 4)      // 2048 float4 groups
#define GROUPS_PER_BLOCK (GROUPS_PER_ROW / SPLIT)  // 1024

__global__ __launch_bounds__(BLOCK)
void spline_partial_kernel(const float* __restrict__ tf,
                           const float* __restrict__ pf,
                           float* __restrict__ partial) {
    const int b    = blockIdx.x >> 1;          // row
    const int half = blockIdx.x & 1;           // which half of the row
    const float4* t4 = (const float4*)(tf + (size_t)b * N_COLS);
    const float4* p4 = (const float4*)(pf + (size_t)b * N_COLS);

    const int g0 = half * GROUPS_PER_BLOCK + threadIdx.x;

    // ---- all 8 loads issued before any use: 8 x global_load_dwordx4 ----
    const float4 a0 = t4[g0];
    const float4 a1 = t4[g0 + 256];
    const float4 a2 = t4[g0 + 512];
    const float4 a3 = t4[g0 + 768];
    const float4 c0 = p4[g0];
    const float4 c1 = p4[g0 + 256];
    const float4 c2 = p4[g0 + 512];
    const float4 c3 = p4[g0 + 768];

    // ---- predicated squared-diff accumulate (VALU is ~1% busy, cheap) ----
    float acc = 0.0f;
    {
        const int r = g0 % 5;                       // 256%5==1: r advances +1/step
        float d;
        d = a0.x - c0.x; acc += (r == 0) ? d * d : 0.0f;
        d = a0.z - c0.z; acc += (r == 2) ? d * d : 0.0f;
        const int r1 = (r + 1 >= 5) ? r - 4 : r + 1;
        d = a1.x - c1.x; acc += (r1 == 0) ? d * d : 0.0f;
        d = a1.z - c1.z; acc += (r1 == 2) ? d * d : 0.0f;
        const int r2 = (r1 + 1 >= 5) ? r1 - 4 : r1 + 1;
        d = a2.x - c2.x; acc += (r2 == 0) ? d * d : 0.0f;
        d = a2.z - c2.z; acc += (r2 == 2) ? d * d : 0.0f;
        const int r3 = (r2 + 1 >= 5) ? r2 - 4 : r2 + 1;
        d = a3.x - c3.x; acc += (r3 == 0) ? d * d : 0.0f;
        d = a3.z - c3.z; acc += (r3 == 2) ? d * d : 0.0f;
    }

    // wave-64 shuffle reduction
    #pragma unroll
    for (int off = 32; off > 0; off >>= 1)
        acc += __shfl_down(acc, off, 64);

    __shared__ float wsum[BLOCK / 64];
    const int lane = threadIdx.x & 63;
    const int wid  = threadIdx.x >> 6;
    if (lane == 0) wsum[wid] = acc;
    __syncthreads();

    if (threadIdx.x == 0) {
        float s = 0.0f;
        #pragma unroll
        for (int w = 0; w < BLOCK / 64; ++w) s += wsum[w];
        partial[blockIdx.x] = s;               // plain store; next dispatch sees it
    }
}

__global__ __launch_bounds__(BLOCK)
void spline_final_kernel(const float* __restrict__ partial,
                         float* __restrict__ out) {
    float acc = 0.0f;
    #pragma unroll
    for (int k = 0; k < GRID / BLOCK; ++k)     // 8 coalesced loads
        acc += partial[k * BLOCK + threadIdx.x];

    #pragma unroll
    for (int off = 32; off > 0; off >>= 1)
        acc += __shfl_down(acc, off, 64);

    __shared__ float wsum[BLOCK / 64];
    const int lane = threadIdx.x & 63;
    const int wid  = threadIdx.x >> 6;
    if (lane == 0) wsum[wid] = acc;
    __syncthreads();

    if (threadIdx.x == 0) {
        float s = 0.0f;
        #pragma unroll
        for (int w = 0; w < BLOCK / 64; ++w) s += wsum[w];
        out[0] = s * (1.0f / (float)(B_ROWS * N_SAMP));  // overwrite, no memset
    }
}

extern "C" void kernel_launch(void* const* d_in, const int* in_sizes, int n_in,
                              void* d_out, int out_size, void* d_ws, size_t ws_size,
                              hipStream_t stream) {
    const float* tf = (const float*)d_in[0];   // true_frames  (1024, 8192) f32
    const float* pf = (const float*)d_in[1];   // predicted_frames
    float* out     = (float*)d_out;            // scalar f32
    float* partial = (float*)d_ws;             // 2048 floats of scratch

    spline_partial_kernel<<<GRID, BLOCK, 0, stream>>>(tf, pf, partial);
    spline_final_kernel<<<1, BLOCK, 0, stream>>>(partial, out);
}

// Round 2
// 91.649 us; speedup vs baseline: 1.0318x; 1.0318x over previous
//
#include <hip/hip_runtime.h>
#include <hip/hip_bf16.h>

// SplineLoss: reference evaluates a not-a-knot cubic spline at INTEGER sample
// times t=0,10,...,8190 with knots at integers 0..8191 -> local parameter is
// exactly 0 for every sample, so the spline solve vanishes and the result is
// exactly:  mean_{b<1024, j<820} (true[b,10j] - pred[b,10j])^2
//
// Stride 40B < 64B line -> every line of both 32MB inputs is needed; minimum
// traffic 64MB, roofline ~10.2us at 6.3TB/s. Within float4 group g (t=4g),
// samples land at .x when g%5==0 and .z when g%5==2.
//
// R3 lesson 1: per-block agent-scope acq_rel fences are catastrophic
// (~+90us for 2048 blocks) -> two-dispatch reduction, no device fences.
// R3 lesson 2: named-register loads -> 8 global_load_dwordx4 in flight.
//
// R5 model (from R4 counters): top-5 dispatches are all 268MB ws-poison
// fills at 5.9-6.3 TB/s (DVFS floor REJECTED; chip sustains 6.2 TB/s).
// Our partial kernel is absent from top-5 -> dur < 42.4us. Decomposition:
// fill ~44 + partial ~41 + final ~3 + overhead ~6 = 94.6us. So partial runs
// at 64MB/41us = 1.56 TB/s = 25% of attainable, despite 256KB/CU in flight
// (vs 9.2KB needed) -> NOT latency-bound; suspect L1/L2 line-allocation
// tracking cap (~64 lines/CU -> ~4KB effective MLP -> ~1.7 TB/s, matches).
// This kernel has ZERO reuse: each 64B line feeds exactly one dwordx4 once.
// R5 change (single mechanism): volatile vector loads -> sc0 sc1 on gfx950
// -> no L1/L2 allocation; bypassed loads tracked per-wave by vmcnt only.
// Predict: partial ~41 -> ~12-16us, dur_us 94.6 -> ~62-70.
// Null (92-96) -> floor dominates, pivot. Regression -> cache-resident path,
// pivot to residency.

#define B_ROWS   1024
#define N_COLS   8192
#define N_SAMP   820
#define BLOCK    256
#define SPLIT    2                         // blocks per row
#define GRID     (B_ROWS * SPLIT)          // 2048 partials
#define GROUPS_PER_ROW   (N_COLS / 4)      // 2048 float4 groups
#define GROUPS_PER_BLOCK (GROUPS_PER_ROW / SPLIT)  // 1024

typedef float f4 __attribute__((ext_vector_type(4)));

__global__ __launch_bounds__(BLOCK)
void spline_partial_kernel(const float* __restrict__ tf,
                           const float* __restrict__ pf,
                           float* __restrict__ partial) {
    const int b    = blockIdx.x >> 1;          // row
    const int half = blockIdx.x & 1;           // which half of the row
    // volatile -> sc0 sc1 system-scope loads: no L1/L2 allocation, pure
    // streaming. Zero-reuse kernel, so bypass is semantically free.
    const volatile f4* t4 = (const volatile f4*)(tf + (size_t)b * N_COLS);
    const volatile f4* p4 = (const volatile f4*)(pf + (size_t)b * N_COLS);

    const int g0 = half * GROUPS_PER_BLOCK + threadIdx.x;

    // ---- all 8 loads issued before any use: 8 x global_load_dwordx4 ----
    const f4 a0 = t4[g0];
    const f4 a1 = t4[g0 + 256];
    const f4 a2 = t4[g0 + 512];
    const f4 a3 = t4[g0 + 768];
    const f4 c0 = p4[g0];
    const f4 c1 = p4[g0 + 256];
    const f4 c2 = p4[g0 + 512];
    const f4 c3 = p4[g0 + 768];

    // ---- predicated squared-diff accumulate (VALU is ~1% busy, cheap) ----
    float acc = 0.0f;
    {
        const int r = g0 % 5;                       // 256%5==1: r advances +1/step
        float d;
        d = a0[0] - c0[0]; acc += (r == 0) ? d * d : 0.0f;
        d = a0[2] - c0[2]; acc += (r == 2) ? d * d : 0.0f;
        const int r1 = (r + 1 >= 5) ? r - 4 : r + 1;
        d = a1[0] - c1[0]; acc += (r1 == 0) ? d * d : 0.0f;
        d = a1[2] - c1[2]; acc += (r1 == 2) ? d * d : 0.0f;
        const int r2 = (r1 + 1 >= 5) ? r1 - 4 : r1 + 1;
        d = a2[0] - c2[0]; acc += (r2 == 0) ? d * d : 0.0f;
        d = a2[2] - c2[2]; acc += (r2 == 2) ? d * d : 0.0f;
        const int r3 = (r2 + 1 >= 5) ? r2 - 4 : r2 + 1;
        d = a3[0] - c3[0]; acc += (r3 == 0) ? d * d : 0.0f;
        d = a3[2] - c3[2]; acc += (r3 == 2) ? d * d : 0.0f;
    }

    // wave-64 shuffle reduction
    #pragma unroll
    for (int off = 32; off > 0; off >>= 1)
        acc += __shfl_down(acc, off, 64);

    __shared__ float wsum[BLOCK / 64];
    const int lane = threadIdx.x & 63;
    const int wid  = threadIdx.x >> 6;
    if (lane == 0) wsum[wid] = acc;
    __syncthreads();

    if (threadIdx.x == 0) {
        float s = 0.0f;
        #pragma unroll
        for (int w = 0; w < BLOCK / 64; ++w) s += wsum[w];
        partial[blockIdx.x] = s;               // plain store; next dispatch sees it
    }
}

__global__ __launch_bounds__(BLOCK)
void spline_final_kernel(const float* __restrict__ partial,
                         float* __restrict__ out) {
    float acc = 0.0f;
    #pragma unroll
    for (int k = 0; k < GRID / BLOCK; ++k)     // 8 coalesced loads
        acc += partial[k * BLOCK + threadIdx.x];

    #pragma unroll
    for (int off = 32; off > 0; off >>= 1)
        acc += __shfl_down(acc, off, 64);

    __shared__ float wsum[BLOCK / 64];
    const int lane = threadIdx.x & 63;
    const int wid  = threadIdx.x >> 6;
    if (lane == 0) wsum[wid] = acc;
    __syncthreads();

    if (threadIdx.x == 0) {
        float s = 0.0f;
        #pragma unroll
        for (int w = 0; w < BLOCK / 64; ++w) s += wsum[w];
        out[0] = s * (1.0f / (float)(B_ROWS * N_SAMP));  // overwrite, no memset
    }
}

extern "C" void kernel_launch(void* const* d_in, const int* in_sizes, int n_in,
                              void* d_out, int out_size, void* d_ws, size_t ws_size,
                              hipStream_t stream) {
    const float* tf = (const float*)d_in[0];   // true_frames  (1024, 8192) f32
    const float* pf = (const float*)d_in[1];   // predicted_frames
    float* out     = (float*)d_out;            // scalar f32
    float* partial = (float*)d_ws;             // 2048 floats of scratch

    spline_partial_kernel<<<GRID, BLOCK, 0, stream>>>(tf, pf, partial);
    spline_final_kernel<<<1, BLOCK, 0, stream>>>(partial, out);
}